// Round 10
// baseline (227.151 us; speedup 1.0000x reference)
//
#include <hip/hip_runtime.h>
#include <hip/hip_bf16.h>
#include <math.h>

#define TOTAL_Q   2048
#define TOTAL_KV  2048
#define QIN       1024
#define KVIN      1033
#define KVIN_P    1056      // KVIN padded to multiple of 32 (zero-filled)
#define DQK       1024
#define DV        1024
#define SCALER    0.125f    // 1/sqrt(64)

typedef __bf16 bf16x8 __attribute__((ext_vector_type(8)));
typedef float  f32x4  __attribute__((ext_vector_type(4)));

// async global->LDS, 16 B per lane; LDS dest = wave-uniform base + lane*16
__device__ __forceinline__ void glds16(const __hip_bfloat16* g, __bf16* l)
{
    __builtin_amdgcn_global_load_lds(
        (const __attribute__((address_space(1))) void*)g,
        (__attribute__((address_space(3))) void*)l,
        16, 0, 0);
}

// XOR-swizzled LDS tile layout (proven R7): slot = quad ^ ((row>>1)&3)
__device__ __forceinline__ int stage_cc(int lane)
{
    return (((lane & 3) ^ ((lane >> 3) & 3)) * 8);
}
__device__ __forceinline__ int frag_off(int row, int quad)
{
    return row * 32 + ((quad ^ ((row >> 1) & 3)) * 8);
}

// ---------------------------------------------------------------------------
// Fused prep (unchanged, proven): casts, weight transposes, out-bias init.
// ---------------------------------------------------------------------------
__global__ __launch_bounds__(256)
void prep_k(const float* __restrict__ A,  const float* __restrict__ B0,
            const float* __restrict__ Wq, const float* __restrict__ Wk,
            const float* __restrict__ Wv, const float* __restrict__ Wf,
            const float* __restrict__ bf,
            __hip_bfloat16* __restrict__ Abf, __hip_bfloat16* __restrict__ B0bf,
            __hip_bfloat16* __restrict__ Wqt, __hip_bfloat16* __restrict__ Wkt,
            __hip_bfloat16* __restrict__ Wvt, __hip_bfloat16* __restrict__ Wft,
            float* __restrict__ outp)
{
    const int b   = blockIdx.x;
    const int tid = threadIdx.x;

    if (b < 2048) {                       // ---- cast A
        int i = (b * 256 + tid) * 4;
        float4 f = *(const float4*)(A + i);
        __hip_bfloat16 o[4] = { __float2bfloat16(f.x), __float2bfloat16(f.y),
                                __float2bfloat16(f.z), __float2bfloat16(f.w) };
        *(uint2*)(Abf + i) = *(const uint2*)o;
        return;
    }
    if (b < 4160) {                       // ---- cast+pad B0
        int idx = ((b - 2048) * 256 + tid) * 4;
        int r = idx / KVIN_P, c = idx - r * KVIN_P;
        __hip_bfloat16 o[4];
        #pragma unroll
        for (int j = 0; j < 4; ++j)
            o[j] = __float2bfloat16((c + j < KVIN) ? B0[(size_t)r * KVIN + c + j] : 0.f);
        *(uint2*)(B0bf + idx) = *(const uint2*)o;
        return;
    }
    if (b >= 8320) {                      // ---- out = bias (broadcast rows)
        int idx = ((b - 8320) * 256 + tid) * 4;
        int c = idx & 1023;
        float4 o = { bf[c], bf[c + 1], bf[c + 2], bf[c + 3] };
        *(float4*)(outp + idx) = o;
        return;
    }

    // ---- transposes: W[K][1024] -> Wt[1024][Kp], zero-fill k >= K
    const float* W; __hip_bfloat16* Wt; int K, Kp, k0, n0;
    if (b < 6208) {
        int z = b - 4160;
        W  = (z >= 1024) ? Wf : Wq;
        Wt = (z >= 1024) ? Wft : Wqt;
        K = 1024; Kp = 1024;
        int rem = z & 1023;
        k0 = (rem & 31) * 32; n0 = (rem >> 5) * 32;
    } else {
        int z = b - 6208;
        W  = (z >= 1056) ? Wv : Wk;
        Wt = (z >= 1056) ? Wvt : Wkt;
        K = KVIN; Kp = KVIN_P;
        int rem = (z >= 1056) ? z - 1056 : z;
        k0 = (rem % 33) * 32; n0 = (rem / 33) * 32;
    }
    const int tx = tid & 31, ty = tid >> 5;   // (32,8)
    __shared__ float tile[32][33];
    #pragma unroll
    for (int i = 0; i < 4; ++i) {
        int k = k0 + ty + i * 8;
        tile[ty + i * 8][tx] = (k < K) ? W[(size_t)k * 1024 + n0 + tx] : 0.f;
    }
    __syncthreads();
    #pragma unroll
    for (int i = 0; i < 4; ++i) {
        int n = n0 + ty + i * 8;
        Wt[(size_t)n * Kp + k0 + tx] = __float2bfloat16(tile[tx][ty + i * 8]);
    }
}

// ---------------------------------------------------------------------------
// FUSED attention: per (segment, head) block, compute q/k/v projections
// in-kernel (glds16-staged MFMA GEMM tiles) and run the flash-attention core
// directly on the LDS results. No qb/kvb intermediates.
//   per q-tile (64 rows):  q-proj 64x64 @ K=1024 -> qS LDS -> q A-frags
//   per kv-chunk (64 rows): k|v-proj 64x(64+64) @ K=1056 -> Ks/Vt LDS
//   attn core: S = q@k^T, masked online softmax, P via LDS, O += P@V  (proven)
// Layouts identical to the proven gemm/attn kernels.
// ---------------------------------------------------------------------------
__global__ __launch_bounds__(256)
void attn_fused(const __hip_bfloat16* __restrict__ Abf,
                const __hip_bfloat16* __restrict__ B0bf,
                const __hip_bfloat16* __restrict__ Wqt,
                const __hip_bfloat16* __restrict__ Wkvt,   // Wkt rows 0..1023, Wvt rows 1024..2047
                const float* __restrict__ bq, const float* __restrict__ bk,
                const float* __restrict__ bv,
                const int* __restrict__ seg_q, const int* __restrict__ seg_kv,
                __hip_bfloat16* __restrict__ wv)
{
    const int h = blockIdx.x & 15;
    const int s = blockIdx.x >> 4;

    __shared__ int sb[4];
    __shared__ __bf16 qS[64][72];        // q-tile result [qrow][d]
    __shared__ __bf16 Ks[64][72];        // k-chunk [kvrow][d]
    __shared__ __bf16 Vt[64][72];        // v-chunk transposed [d][kvrow]
    __shared__ __bf16 Ps[4][16][72];     // per-wave P
    __shared__ __bf16 As[64 * 32];       // staging: A rows (4 KB)
    __shared__ __bf16 Bs[64 * 32];       // staging: Wq / Wk rows
    __shared__ __bf16 Bs2[64 * 32];      // staging: Wv rows

    if (threadIdx.x == 0) {
        int lo, hi;
        lo = 0; hi = TOTAL_Q;
        while (lo < hi) { int m = (lo + hi) >> 1; if (seg_q[m] <  s) lo = m + 1; else hi = m; }
        sb[0] = lo;
        hi = TOTAL_Q;
        while (lo < hi) { int m = (lo + hi) >> 1; if (seg_q[m] <= s) lo = m + 1; else hi = m; }
        sb[1] = lo;
        lo = 0; hi = TOTAL_KV;
        while (lo < hi) { int m = (lo + hi) >> 1; if (seg_kv[m] <  s) lo = m + 1; else hi = m; }
        sb[2] = lo;
        hi = TOTAL_KV;
        while (lo < hi) { int m = (lo + hi) >> 1; if (seg_kv[m] <= s) lo = m + 1; else hi = m; }
        sb[3] = lo;
    }
    __syncthreads();
    const int qbeg = sb[0], qend = sb[1], kbeg = sb[2], kend = sb[3];

    const int tid  = threadIdx.x;
    const int wave = tid >> 6, lane = tid & 63;
    const int quad = lane >> 4, l16 = lane & 15;

    const int cr = lane >> 2;          // staging row within 16-row chunk
    const int cc = stage_cc(lane);     // swizzled k-offset

    // per-lane bias values for this head's 64-col slice (col = nt*16 + l16)
    float bqv[4], bkv[4], bvv[4];
    #pragma unroll
    for (int nt = 0; nt < 4; ++nt) {
        bqv[nt] = bq[h * 64 + nt * 16 + l16];
        bkv[nt] = bk[h * 64 + nt * 16 + l16];
        bvv[nt] = bv[h * 64 + nt * 16 + l16];
    }

    // KV staging sources independent of q-tile / chunk base row: precompute W parts
    // wave w stages chunks 3w..3w+2 of 12: 0..3 -> B0 rows (As), 4..7 -> Wk (Bs),
    // 8..11 -> Wv (Bs2)
    const __hip_bfloat16* kv_wsrc[3];  // only for chunks >= 4 (weight rows)
    __bf16* kv_dst[3];
    int kv_achunk[3];                  // -1 if weight chunk
    #pragma unroll
    for (int i = 0; i < 3; ++i) {
        int c = wave * 3 + i;
        if (c < 4) {
            kv_achunk[i] = c;
            kv_wsrc[i] = nullptr;
            kv_dst[i] = &As[c * 512];
        } else if (c < 8) {
            kv_achunk[i] = -1;
            kv_wsrc[i] = Wkvt + (size_t)(h * 64 + (c - 4) * 16 + cr) * KVIN_P + cc;
            kv_dst[i] = &Bs[(c - 4) * 512];
        } else {
            kv_achunk[i] = -1;
            kv_wsrc[i] = Wkvt + (size_t)(1024 + h * 64 + (c - 8) * 16 + cr) * KVIN_P + cc;
            kv_dst[i] = &Bs2[(c - 8) * 512];
        }
    }

    for (int qt = qbeg; qt < qend; qt += 64) {
        // ================= Q-PROJECTION: 64 rows x 64 cols @ K=1024 ============
        {
            // wave w stages chunks 2w, 2w+1 of 8 (0..3 A-rows, 4..7 Wq-rows)
            const __hip_bfloat16* gsrc[2];
            __bf16* ldst[2];
            #pragma unroll
            for (int i = 0; i < 2; ++i) {
                int c = wave * 2 + i;
                if (c < 4) {
                    int g = min(qt + c * 16 + cr, qend - 1);   // clamp (dup rows discarded)
                    gsrc[i] = Abf + (size_t)g * QIN + cc;
                    ldst[i] = &As[c * 512];
                } else {
                    gsrc[i] = Wqt + (size_t)(h * 64 + (c - 4) * 16 + cr) * DQK + cc;
                    ldst[i] = &Bs[(c - 4) * 512];
                }
            }

            f32x4 accq[4] = {};
            for (int k0 = 0; k0 < 1024; k0 += 32) {
                glds16(gsrc[0] + k0, ldst[0]);
                glds16(gsrc[1] + k0, ldst[1]);
                __syncthreads();
                bf16x8 af = *(const bf16x8*)&As[frag_off(wave * 16 + l16, quad)];
                bf16x8 bfr[4];
                #pragma unroll
                for (int nt = 0; nt < 4; ++nt)
                    bfr[nt] = *(const bf16x8*)&Bs[frag_off(nt * 16 + l16, quad)];
                #pragma unroll
                for (int nt = 0; nt < 4; ++nt)
                    accq[nt] = __builtin_amdgcn_mfma_f32_16x16x32_bf16(af, bfr[nt], accq[nt], 0, 0, 0);
                __syncthreads();
            }
            // epilogue: qS[qrow_local][d] = acc + bias   (C: col=l16, row=quad*4+r)
            #pragma unroll
            for (int nt = 0; nt < 4; ++nt)
                #pragma unroll
                for (int r = 0; r < 4; ++r)
                    qS[wave * 16 + quad * 4 + r][nt * 16 + l16] =
                        (__bf16)(accq[nt][r] + bqv[nt]);
        }
        // own-wave rows -> q A-frags (A[m=l16][k=quad*8+j], two k-halves of d=64)
        bf16x8 qf[2];
        qf[0] = *(const bf16x8*)&qS[wave * 16 + l16][quad * 8];
        qf[1] = *(const bf16x8*)&qS[wave * 16 + l16][32 + quad * 8];

        float m[4]  = { -1e30f, -1e30f, -1e30f, -1e30f };
        float l[4]  = { 0.f, 0.f, 0.f, 0.f };
        f32x4 acc[4] = {};

        for (int c0 = kbeg; c0 < kend; c0 += 64) {
            // ================= K|V-PROJECTION: 64 kv rows x (64+64) @ K=1056 =====
            {
                const __hip_bfloat16* gsrc[3];
                #pragma unroll
                for (int i = 0; i < 3; ++i) {
                    if (kv_achunk[i] >= 0) {
                        int g = min(c0 + kv_achunk[i] * 16 + cr, TOTAL_KV - 1); // finite; S-mask covers
                        gsrc[i] = B0bf + (size_t)g * KVIN_P + cc;
                    } else {
                        gsrc[i] = kv_wsrc[i];
                    }
                }

                f32x4 acck[4] = {}, accv[4] = {};
                for (int k0 = 0; k0 < KVIN_P; k0 += 32) {
                    #pragma unroll
                    for (int i = 0; i < 3; ++i)
                        glds16(gsrc[i] + k0, kv_dst[i]);
                    __syncthreads();
                    bf16x8 af = *(const bf16x8*)&As[frag_off(wave * 16 + l16, quad)];
                    bf16x8 bk8[4], bv8[4];
                    #pragma unroll
                    for (int nt = 0; nt < 4; ++nt) {
                        bk8[nt] = *(const bf16x8*)&Bs [frag_off(nt * 16 + l16, quad)];
                        bv8[nt] = *(const bf16x8*)&Bs2[frag_off(nt * 16 + l16, quad)];
                    }
                    #pragma unroll
                    for (int nt = 0; nt < 4; ++nt) {
                        acck[nt] = __builtin_amdgcn_mfma_f32_16x16x32_bf16(af, bk8[nt], acck[nt], 0, 0, 0);
                        accv[nt] = __builtin_amdgcn_mfma_f32_16x16x32_bf16(af, bv8[nt], accv[nt], 0, 0, 0);
                    }
                    __syncthreads();
                }
                // epilogue: Ks[kvrow][d] natural, Vt[d][kvrow] transposed
                #pragma unroll
                for (int nt = 0; nt < 4; ++nt)
                    #pragma unroll
                    for (int r = 0; r < 4; ++r) {
                        const int row = wave * 16 + quad * 4 + r;
                        Ks[row][nt * 16 + l16] = (__bf16)(acck[nt][r] + bkv[nt]);
                        Vt[nt * 16 + l16][row] = (__bf16)(accv[nt][r] + bvv[nt]);
                    }
                __syncthreads();   // Ks/Vt ready for all waves
            }

            // ================= ATTENTION CORE (proven) ==========================
            f32x4 sc[4];
            #pragma unroll
            for (int t = 0; t < 4; ++t) {
                bf16x8 b0 = *(const bf16x8*)&Ks[t * 16 + l16][quad * 8];
                bf16x8 b1 = *(const bf16x8*)&Ks[t * 16 + l16][32 + quad * 8];
                f32x4 z = {};
                z = __builtin_amdgcn_mfma_f32_16x16x32_bf16(qf[0], b0, z, 0, 0, 0);
                z = __builtin_amdgcn_mfma_f32_16x16x32_bf16(qf[1], b1, z, 0, 0, 0);
                sc[t] = z;
            }

            float sv[4][4];
            #pragma unroll
            for (int t = 0; t < 4; ++t) {
                const bool ok = (c0 + t * 16 + l16) < kend;
                #pragma unroll
                for (int r = 0; r < 4; ++r)
                    sv[t][r] = ok ? sc[t][r] * SCALER : -1e30f;
            }

            #pragma unroll
            for (int r = 0; r < 4; ++r) {
                float mx = fmaxf(fmaxf(sv[0][r], sv[1][r]), fmaxf(sv[2][r], sv[3][r]));
                mx = fmaxf(mx, __shfl_xor(mx, 1));
                mx = fmaxf(mx, __shfl_xor(mx, 2));
                mx = fmaxf(mx, __shfl_xor(mx, 4));
                mx = fmaxf(mx, __shfl_xor(mx, 8));
                const float mn = fmaxf(m[r], mx);
                const float alpha = __expf(m[r] - mn);
                m[r] = mn;
                float rs = 0.f;
                #pragma unroll
                for (int t = 0; t < 4; ++t) {
                    const float p = __expf(sv[t][r] - mn);
                    sv[t][r] = p;
                    rs += p;
                }
                rs += __shfl_xor(rs, 1);
                rs += __shfl_xor(rs, 2);
                rs += __shfl_xor(rs, 4);
                rs += __shfl_xor(rs, 8);
                l[r] = l[r] * alpha + rs;
                #pragma unroll
                for (int dt = 0; dt < 4; ++dt) acc[dt][r] *= alpha;
            }

            #pragma unroll
            for (int t = 0; t < 4; ++t)
                #pragma unroll
                for (int r = 0; r < 4; ++r)
                    Ps[wave][quad * 4 + r][t * 16 + l16] = (__bf16)sv[t][r];
            __syncthreads();

            #pragma unroll
            for (int ks = 0; ks < 2; ++ks) {
                bf16x8 pa = *(const bf16x8*)&Ps[wave][l16][ks * 32 + quad * 8];
                #pragma unroll
                for (int dt = 0; dt < 4; ++dt) {
                    bf16x8 vbf = *(const bf16x8*)&Vt[dt * 16 + l16][ks * 32 + quad * 8];
                    acc[dt] = __builtin_amdgcn_mfma_f32_16x16x32_bf16(pa, vbf, acc[dt], 0, 0, 0);
                }
            }
            // next chunk's staging barrier orders Ks/Vt/Ps reuse
        }

        float inv[4];
        #pragma unroll
        for (int r = 0; r < 4; ++r) inv[r] = 1.f / l[r];
        #pragma unroll
        for (int dt = 0; dt < 4; ++dt) {
            #pragma unroll
            for (int r = 0; r < 4; ++r) {
                const int row = qt + wave * 16 + quad * 4 + r;
                if (row < qend)
                    wv[(size_t)row * DV + h * 64 + dt * 16 + l16] =
                        __float2bfloat16(acc[dt][r] * inv[r]);
            }
        }
        __syncthreads();   // qS reuse in next q-tile
    }
}

// ---------------------------------------------------------------------------
// Output projection (unchanged from R9): split-K=2, double-buffered glds16,
// atomicAdd onto bias-initialized out. BM=128, BN=64, BK=32.
// ---------------------------------------------------------------------------
__global__ __launch_bounds__(256)
void gemm_out(const __hip_bfloat16* __restrict__ A,
              const __hip_bfloat16* __restrict__ Bt,
              float* __restrict__ C,
              int M, int N, int K)
{
    __shared__ __bf16 As[2][128 * 32];
    __shared__ __bf16 Bs[2][64 * 32];

    const int tid  = threadIdx.x;
    const int wave = tid >> 6, lane = tid & 63;
    const int quad = lane >> 4, l16 = lane & 15;
    const int wm = (wave >> 1) * 64;
    const int wn = (wave & 1) * 32;
    const int row0 = blockIdx.y * 128, col0 = blockIdx.x * 64;
    const int kz0 = blockIdx.z * (K / 2), kz1 = kz0 + K / 2;

    const int cr = lane >> 2;
    const int cc = stage_cc(lane);

    const __hip_bfloat16* gsrc[3];
    __bf16* ldst[2][3];
    #pragma unroll
    for (int i = 0; i < 3; ++i) {
        int c = wave * 3 + i;
        if (c < 8) {
            gsrc[i] = A  + (size_t)(row0 + c * 16 + cr) * K + cc;
            ldst[0][i] = &As[0][c * 512];
            ldst[1][i] = &As[1][c * 512];
        } else {
            gsrc[i] = Bt + (size_t)(col0 + (c - 8) * 16 + cr) * K + cc;
            ldst[0][i] = &Bs[0][(c - 8) * 512];
            ldst[1][i] = &Bs[1][(c - 8) * 512];
        }
    }

    f32x4 acc[4][2] = {};

    #pragma unroll
    for (int i = 0; i < 3; ++i)
        glds16(gsrc[i] + kz0, ldst[0][i]);

    int cur = 0;
    for (int k0 = kz0; k0 < kz1; k0 += 32) {
        __syncthreads();

        if (k0 + 32 < kz1) {
            #pragma unroll
            for (int i = 0; i < 3; ++i)
                glds16(gsrc[i] + k0 + 32, ldst[cur ^ 1][i]);
        }

        const __bf16* Ac = As[cur];
        const __bf16* Bc = Bs[cur];
        bf16x8 af[4], bfr[2];
        #pragma unroll
        for (int mi = 0; mi < 4; ++mi)
            af[mi] = *(const bf16x8*)&Ac[frag_off(wm + mi * 16 + l16, quad)];
        #pragma unroll
        for (int ni = 0; ni < 2; ++ni)
            bfr[ni] = *(const bf16x8*)&Bc[frag_off(wn + ni * 16 + l16, quad)];

        #pragma unroll
        for (int mi = 0; mi < 4; ++mi)
            #pragma unroll
            for (int ni = 0; ni < 2; ++ni)
                acc[mi][ni] = __builtin_amdgcn_mfma_f32_16x16x32_bf16(
                    af[mi], bfr[ni], acc[mi][ni], 0, 0, 0);
        cur ^= 1;
    }

    #pragma unroll
    for (int mi = 0; mi < 4; ++mi) {
        #pragma unroll
        for (int ni = 0; ni < 2; ++ni) {
            const int col = col0 + wn + ni * 16 + l16;
            #pragma unroll
            for (int r = 0; r < 4; ++r) {
                const int row = row0 + wm + mi * 16 + quad * 4 + r;
                atomicAdd(&C[(size_t)row * N + col], acc[mi][ni][r]);
            }
        }
    }
}

// ---------------------------------------------------------------------------
extern "C" void kernel_launch(void* const* d_in, const int* in_sizes, int n_in,
                              void* d_out, int out_size, void* d_ws, size_t ws_size,
                              hipStream_t stream)
{
    const float* A     = (const float*)d_in[0];
    const float* B0    = (const float*)d_in[1];
    const int*   seg_q = (const int*)  d_in[2];
    const int*   seg_kv= (const int*)  d_in[3];
    const float* Wq    = (const float*)d_in[4];
    const float* bq    = (const float*)d_in[5];
    const float* Wk    = (const float*)d_in[6];
    const float* bk    = (const float*)d_in[7];
    const float* Wv    = (const float*)d_in[8];
    const float* bv    = (const float*)d_in[9];
    const float* Wf    = (const float*)d_in[10];
    const float* bf    = (const float*)d_in[11];
    float* out = (float*)d_out;

    // Workspace (bf16 elems); all offsets 16B-aligned
    __hip_bfloat16* B0bf = (__hip_bfloat16*)d_ws;                 // 2048*1056
    __hip_bfloat16* Wqt  = B0bf + (size_t)TOTAL_KV * KVIN_P;      // 1024*1024
    __hip_bfloat16* Wkt  = Wqt  + (size_t)QIN * DQK;              // 1024*1056  \ fused Wkvt
    __hip_bfloat16* Wvt  = Wkt  + (size_t)DQK * KVIN_P;           // 1024*1056  /
    __hip_bfloat16* Wft  = Wvt  + (size_t)DV * KVIN_P;            // 1024*1024
    __hip_bfloat16* Abf  = Wft  + (size_t)DV * QIN;               // 2048*1024 (live through attn)
    __hip_bfloat16* wvb  = Abf  + (size_t)TOTAL_Q * QIN;          // 2048*1024 (own buffer)

    const dim3 b256(256);

    // 1) prep: casts + weight transposes + out-bias init
    prep_k<<<dim3(10368), b256, 0, stream>>>(A, B0, Wq, Wk, Wv, Wf, bf,
                                             Abf, B0bf, Wqt, Wkt, Wvt, Wft, out);

    // 2) fused q/k/v projection + attention: block per (segment, head)
    attn_fused<<<dim3(32 * 16), b256, 0, stream>>>(Abf, B0bf, Wqt, Wkt,
                                                   bq, bk, bv, seg_q, seg_kv, wvb);

    // 3) output projection, split-K=2, atomic accumulate onto bias-initialized out
    gemm_out<<<dim3(QIN / 64, TOTAL_Q / 128, 2), b256, 0, stream>>>(
        wvb, Wft, out, TOTAL_Q, QIN, DV);
}

// Round 11
// 168.120 us; speedup vs baseline: 1.3511x; 1.3511x over previous
//
#include <hip/hip_runtime.h>
#include <hip/hip_bf16.h>
#include <math.h>

#define TOTAL_Q   2048
#define TOTAL_KV  2048
#define QIN       1024
#define KVIN      1033
#define KVIN_P    1056      // KVIN padded to multiple of 32 (zero-filled)
#define DQK       1024
#define DV        1024
#define KVSTR     2048      // fused [k|v] row stride
#define SCALER    0.125f    // 1/sqrt(64)

typedef __bf16 bf16x8 __attribute__((ext_vector_type(8)));
typedef float  f32x4  __attribute__((ext_vector_type(4)));

// async global->LDS, 16 B per lane; LDS dest = wave-uniform base + lane*16
__device__ __forceinline__ void glds16(const __hip_bfloat16* g, __bf16* l)
{
    __builtin_amdgcn_global_load_lds(
        (const __attribute__((address_space(1))) void*)g,
        (__attribute__((address_space(3))) void*)l,
        16, 0, 0);
}

// XOR-swizzled LDS tile layout (proven R7): slot = quad ^ ((row>>1)&3)
__device__ __forceinline__ int stage_cc(int lane)
{
    return (((lane & 3) ^ ((lane >> 3) & 3)) * 8);
}
__device__ __forceinline__ int frag_off(int row, int quad)
{
    return row * 32 + ((quad ^ ((row >> 1) & 3)) * 8);
}

// ---------------------------------------------------------------------------
// Fused prep (unchanged, proven): casts, weight transposes, out-bias init.
// ---------------------------------------------------------------------------
__global__ __launch_bounds__(256)
void prep_k(const float* __restrict__ A,  const float* __restrict__ B0,
            const float* __restrict__ Wq, const float* __restrict__ Wk,
            const float* __restrict__ Wv, const float* __restrict__ Wf,
            const float* __restrict__ bf,
            __hip_bfloat16* __restrict__ Abf, __hip_bfloat16* __restrict__ B0bf,
            __hip_bfloat16* __restrict__ Wqt, __hip_bfloat16* __restrict__ Wkt,
            __hip_bfloat16* __restrict__ Wvt, __hip_bfloat16* __restrict__ Wft,
            float* __restrict__ outp)
{
    const int b   = blockIdx.x;
    const int tid = threadIdx.x;

    if (b < 2048) {                       // ---- cast A
        int i = (b * 256 + tid) * 4;
        float4 f = *(const float4*)(A + i);
        __hip_bfloat16 o[4] = { __float2bfloat16(f.x), __float2bfloat16(f.y),
                                __float2bfloat16(f.z), __float2bfloat16(f.w) };
        *(uint2*)(Abf + i) = *(const uint2*)o;
        return;
    }
    if (b < 4160) {                       // ---- cast+pad B0
        int idx = ((b - 2048) * 256 + tid) * 4;
        int r = idx / KVIN_P, c = idx - r * KVIN_P;
        __hip_bfloat16 o[4];
        #pragma unroll
        for (int j = 0; j < 4; ++j)
            o[j] = __float2bfloat16((c + j < KVIN) ? B0[(size_t)r * KVIN + c + j] : 0.f);
        *(uint2*)(B0bf + idx) = *(const uint2*)o;
        return;
    }
    if (b >= 8320) {                      // ---- out = bias (broadcast rows)
        int idx = ((b - 8320) * 256 + tid) * 4;
        int c = idx & 1023;
        float4 o = { bf[c], bf[c + 1], bf[c + 2], bf[c + 3] };
        *(float4*)(outp + idx) = o;
        return;
    }

    // ---- transposes: W[K][1024] -> Wt[1024][Kp], zero-fill k >= K
    const float* W; __hip_bfloat16* Wt; int K, Kp, k0, n0;
    if (b < 6208) {
        int z = b - 4160;
        W  = (z >= 1024) ? Wf : Wq;
        Wt = (z >= 1024) ? Wft : Wqt;
        K = 1024; Kp = 1024;
        int rem = z & 1023;
        k0 = (rem & 31) * 32; n0 = (rem >> 5) * 32;
    } else {
        int z = b - 6208;
        W  = (z >= 1056) ? Wv : Wk;
        Wt = (z >= 1056) ? Wvt : Wkt;
        K = KVIN; Kp = KVIN_P;
        int rem = (z >= 1056) ? z - 1056 : z;
        k0 = (rem % 33) * 32; n0 = (rem / 33) * 32;
    }
    const int tx = tid & 31, ty = tid >> 5;   // (32,8)
    __shared__ float tile[32][33];
    #pragma unroll
    for (int i = 0; i < 4; ++i) {
        int k = k0 + ty + i * 8;
        tile[ty + i * 8][tx] = (k < K) ? W[(size_t)k * 1024 + n0 + tx] : 0.f;
    }
    __syncthreads();
    #pragma unroll
    for (int i = 0; i < 4; ++i) {
        int n = n0 + ty + i * 8;
        Wt[(size_t)n * Kp + k0 + tx] = __float2bfloat16(tile[tx][ty + i * 8]);
    }
}

// ---------------------------------------------------------------------------
// Grouped Q + fused-KV projection (R7 structure) + XCD-aware block swizzle.
// BM=128, BN=64, BK=32 -> 768 blocks (3/CU). blockIdx%8 ~ XCD (round-robin);
// each XCD gets a compact tile patch so its 4 MB L2 holds the patch operands:
//   Q part  (16c x 16r): patch 4 cols x 8 rows  -> ~2.5 MB/XCD
//   KV part (32c x 16r): patch 8 cols x 8 rows  -> ~3.3 MB/XCD
// ---------------------------------------------------------------------------
__global__ __launch_bounds__(256)
void gemm_qkv(const __hip_bfloat16* __restrict__ Abf,
              const __hip_bfloat16* __restrict__ Wqt,
              const float* __restrict__ bq,
              __hip_bfloat16* __restrict__ qb,
              const __hip_bfloat16* __restrict__ B0bf,
              const __hip_bfloat16* __restrict__ Wkvt,
              const float* __restrict__ bk, const float* __restrict__ bv,
              __hip_bfloat16* __restrict__ kvb)
{
    __shared__ __bf16 As[128 * 32];   // 8 KB
    __shared__ __bf16 Bs[64 * 32];    // 4 KB

    int b = blockIdx.x;
    const __hip_bfloat16 *Ag, *Btg; const float *bias0, *bias1;
    __hip_bfloat16* C; int N, K, bx, by;
    if (b < 256) {        // Q: 16 cols x 16 rows, XCD patch 4x8
        Ag = Abf; Btg = Wqt; bias0 = bq; bias1 = bq; C = qb;
        N = 1024; K = 1024;
        int xcd = b & 7, i = b >> 3;              // i in [0,32)
        int px = xcd & 3, py = xcd >> 2;
        bx = px * 4 + (i & 3);
        by = py * 8 + (i >> 2);
    } else {              // KV: 32 cols x 16 rows, XCD patch 8x8
        b -= 256;
        Ag = B0bf; Btg = Wkvt; bias0 = bk; bias1 = bv; C = kvb;
        N = 2048; K = KVIN_P;
        int xcd = b & 7, i = b >> 3;              // i in [0,64)
        int px = xcd & 3, py = xcd >> 2;
        bx = px * 8 + (i & 7);
        by = py * 8 + (i >> 3);
    }
    const int row0 = by * 128, col0 = bx * 64;

    const int tid  = threadIdx.x;
    const int wave = tid >> 6, lane = tid & 63;
    const int quad = lane >> 4, l16 = lane & 15;
    const int wm = (wave >> 1) * 64, wn = (wave & 1) * 32;

    const int cr = lane >> 2;          // staging row within chunk
    const int cc = stage_cc(lane);     // swizzled global elem offset

    const __hip_bfloat16* gsrc[3];
    __bf16* ldst[3];
    #pragma unroll
    for (int i = 0; i < 3; ++i) {
        int c = wave * 3 + i;
        if (c < 8) {
            gsrc[i] = Ag  + (size_t)(row0 + c * 16 + cr) * K + cc;
            ldst[i] = &As[c * 512];
        } else {
            gsrc[i] = Btg + (size_t)(col0 + (c - 8) * 16 + cr) * K + cc;
            ldst[i] = &Bs[(c - 8) * 512];
        }
    }

    f32x4 acc[4][2] = {};

    for (int k0 = 0; k0 < K; k0 += 32) {
        #pragma unroll
        for (int i = 0; i < 3; ++i)
            glds16(gsrc[i] + k0, ldst[i]);
        __syncthreads();

        bf16x8 af[4], bfr[2];
        #pragma unroll
        for (int mi = 0; mi < 4; ++mi)
            af[mi] = *(const bf16x8*)&As[frag_off(wm + mi * 16 + l16, quad)];
        #pragma unroll
        for (int ni = 0; ni < 2; ++ni)
            bfr[ni] = *(const bf16x8*)&Bs[frag_off(wn + ni * 16 + l16, quad)];

        #pragma unroll
        for (int mi = 0; mi < 4; ++mi)
            #pragma unroll
            for (int ni = 0; ni < 2; ++ni)
                acc[mi][ni] = __builtin_amdgcn_mfma_f32_16x16x32_bf16(
                    af[mi], bfr[ni], acc[mi][ni], 0, 0, 0);
        __syncthreads();
    }

    #pragma unroll
    for (int mi = 0; mi < 4; ++mi) {
        #pragma unroll
        for (int ni = 0; ni < 2; ++ni) {
            const int col = col0 + wn + ni * 16 + l16;
            const float bia = (col < 1024) ? bias0[col] : bias1[col - 1024];
            #pragma unroll
            for (int r = 0; r < 4; ++r) {
                const int row = row0 + wm + mi * 16 + quad * 4 + r;
                C[(size_t)row * N + col] = __float2bfloat16(acc[mi][ni][r] + bia);
            }
        }
    }
}

// ---------------------------------------------------------------------------
// Output projection, split-K=2, XCD-patched 1D grid (512 blocks), atomicAdd
// onto bias-initialized out. BM=128, BN=64, BK=32.
// Patch: per XCD, 4 cols x 8 rows x both kz halves -> < 4 MB operand set.
// ---------------------------------------------------------------------------
__global__ __launch_bounds__(256)
void gemm_out(const __hip_bfloat16* __restrict__ A,
              const __hip_bfloat16* __restrict__ Bt,
              float* __restrict__ C,
              int M, int N, int K)   // K = full depth (1024)
{
    __shared__ __bf16 As[128 * 32];
    __shared__ __bf16 Bs[64 * 32];

    // decode: 16 cols x 16 rows x 2 kz; XCD patch 4x8, kz = outer
    int b = blockIdx.x;
    const int xcd = b & 7, i = b >> 3;            // i in [0,64)
    const int px = xcd & 3, py = xcd >> 2;
    const int kz = i >> 5, j = i & 31;
    const int bx = px * 4 + (j & 3);
    const int by = py * 8 + (j >> 2);

    const int tid  = threadIdx.x;
    const int wave = tid >> 6, lane = tid & 63;
    const int quad = lane >> 4, l16 = lane & 15;
    const int wm = (wave >> 1) * 64;
    const int wn = (wave & 1) * 32;
    const int row0 = by * 128, col0 = bx * 64;
    const int kz0 = kz * (K / 2), kz1 = kz0 + K / 2;

    const int cr = lane >> 2;
    const int cc = stage_cc(lane);

    const __hip_bfloat16* gsrc[3];
    __bf16* ldst[3];
    #pragma unroll
    for (int i2 = 0; i2 < 3; ++i2) {
        int c = wave * 3 + i2;
        if (c < 8) {
            gsrc[i2] = A  + (size_t)(row0 + c * 16 + cr) * K + cc;
            ldst[i2] = &As[c * 512];
        } else {
            gsrc[i2] = Bt + (size_t)(col0 + (c - 8) * 16 + cr) * K + cc;
            ldst[i2] = &Bs[(c - 8) * 512];
        }
    }

    f32x4 acc[4][2] = {};

    for (int k0 = kz0; k0 < kz1; k0 += 32) {
        #pragma unroll
        for (int i2 = 0; i2 < 3; ++i2)
            glds16(gsrc[i2] + k0, ldst[i2]);
        __syncthreads();

        bf16x8 af[4], bfr[2];
        #pragma unroll
        for (int mi = 0; mi < 4; ++mi)
            af[mi] = *(const bf16x8*)&As[frag_off(wm + mi * 16 + l16, quad)];
        #pragma unroll
        for (int ni = 0; ni < 2; ++ni)
            bfr[ni] = *(const bf16x8*)&Bs[frag_off(wn + ni * 16 + l16, quad)];

        #pragma unroll
        for (int mi = 0; mi < 4; ++mi)
            #pragma unroll
            for (int ni = 0; ni < 2; ++ni)
                acc[mi][ni] = __builtin_amdgcn_mfma_f32_16x16x32_bf16(
                    af[mi], bfr[ni], acc[mi][ni], 0, 0, 0);
        __syncthreads();
    }

    #pragma unroll
    for (int mi = 0; mi < 4; ++mi) {
        #pragma unroll
        for (int ni = 0; ni < 2; ++ni) {
            const int col = col0 + wn + ni * 16 + l16;
            #pragma unroll
            for (int r = 0; r < 4; ++r) {
                const int row = row0 + wm + mi * 16 + quad * 4 + r;
                atomicAdd(&C[(size_t)row * N + col], acc[mi][ni][r]);
            }
        }
    }
}

// ---------------------------------------------------------------------------
// MFMA flash attention over ragged segments (unchanged, proven).
// ---------------------------------------------------------------------------
#define CH 64

__global__ __launch_bounds__(256)
void attn_mfma(const __hip_bfloat16* __restrict__ qg,
               const __hip_bfloat16* __restrict__ kg,   // kvb
               const __hip_bfloat16* __restrict__ vg,   // kvb + 1024
               const int* __restrict__ seg_q, const int* __restrict__ seg_kv,
               __hip_bfloat16* __restrict__ wv)
{
    const int h = blockIdx.x & 15;
    const int s = blockIdx.x >> 4;

    __shared__ int sb[4];
    __shared__ __bf16 Ks[CH][72];
    __shared__ __bf16 Vt[64][CH + 8];
    __shared__ __bf16 Ps[4][16][CH + 8];

    if (threadIdx.x == 0) {
        int lo, hi;
        lo = 0; hi = TOTAL_Q;
        while (lo < hi) { int m = (lo + hi) >> 1; if (seg_q[m] <  s) lo = m + 1; else hi = m; }
        sb[0] = lo;
        hi = TOTAL_Q;
        while (lo < hi) { int m = (lo + hi) >> 1; if (seg_q[m] <= s) lo = m + 1; else hi = m; }
        sb[1] = lo;
        lo = 0; hi = TOTAL_KV;
        while (lo < hi) { int m = (lo + hi) >> 1; if (seg_kv[m] <  s) lo = m + 1; else hi = m; }
        sb[2] = lo;
        hi = TOTAL_KV;
        while (lo < hi) { int m = (lo + hi) >> 1; if (seg_kv[m] <= s) lo = m + 1; else hi = m; }
        sb[3] = lo;
    }
    __syncthreads();
    const int qbeg = sb[0], qend = sb[1], kbeg = sb[2], kend = sb[3];

    const int tid  = threadIdx.x;
    const int wave = tid >> 6, lane = tid & 63;
    const int quad = lane >> 4, l16 = lane & 15;

    for (int qt = qbeg; qt < qend; qt += 64) {
        const int qrow = qt + wave * 16 + l16;
        const int qrc  = min(qrow, qend - 1);
        bf16x8 qf[2];
        qf[0] = *(const bf16x8*)(qg + (size_t)qrc * DQK + h * 64 + quad * 8);
        qf[1] = *(const bf16x8*)(qg + (size_t)qrc * DQK + h * 64 + 32 + quad * 8);

        float m[4]  = { -1e30f, -1e30f, -1e30f, -1e30f };
        float l[4]  = { 0.f, 0.f, 0.f, 0.f };
        f32x4 acc[4] = {};

        for (int c0 = kbeg; c0 < kend; c0 += CH) {
            const int cl = min(CH, kend - c0);
            __syncthreads();

            #pragma unroll
            for (int it = 0; it < 2; ++it) {
                int e = (it * 256 + tid) * 8;
                int r = e >> 6, d = e & 63;
                bf16x8 z = {};
                if (r < cl)
                    z = *(const bf16x8*)(kg + (size_t)(c0 + r) * KVSTR + h * 64 + d);
                *(bf16x8*)&Ks[r][d] = z;
            }
            #pragma unroll
            for (int it = 0; it < 4; ++it) {
                int e = (it * 256 + tid) * 4;
                int r = e >> 6, d = e & 63;
                __bf16 t0 = 0, t1 = 0, t2 = 0, t3 = 0;
                if (r < cl) {
                    bf16x8 vv;
                    uint2 uu = *(const uint2*)(vg + (size_t)(c0 + r) * KVSTR + h * 64 + d);
                    *(uint2*)&vv = uu;
                    t0 = vv[0]; t1 = vv[1]; t2 = vv[2]; t3 = vv[3];
                }
                Vt[d + 0][r] = t0; Vt[d + 1][r] = t1;
                Vt[d + 2][r] = t2; Vt[d + 3][r] = t3;
            }
            __syncthreads();

            f32x4 sc[4];
            #pragma unroll
            for (int t = 0; t < 4; ++t) {
                bf16x8 b0 = *(const bf16x8*)&Ks[t * 16 + l16][quad * 8];
                bf16x8 b1 = *(const bf16x8*)&Ks[t * 16 + l16][32 + quad * 8];
                f32x4 z = {};
                z = __builtin_amdgcn_mfma_f32_16x16x32_bf16(qf[0], b0, z, 0, 0, 0);
                z = __builtin_amdgcn_mfma_f32_16x16x32_bf16(qf[1], b1, z, 0, 0, 0);
                sc[t] = z;
            }

            float sv[4][4];
            #pragma unroll
            for (int t = 0; t < 4; ++t) {
                const bool ok = (c0 + t * 16 + l16) < kend;
                #pragma unroll
                for (int r = 0; r < 4; ++r)
                    sv[t][r] = ok ? sc[t][r] * SCALER : -1e30f;
            }

            #pragma unroll
            for (int r = 0; r < 4; ++r) {
                float mx = fmaxf(fmaxf(sv[0][r], sv[1][r]), fmaxf(sv[2][r], sv[3][r]));
                mx = fmaxf(mx, __shfl_xor(mx, 1));
                mx = fmaxf(mx, __shfl_xor(mx, 2));
                mx = fmaxf(mx, __shfl_xor(mx, 4));
                mx = fmaxf(mx, __shfl_xor(mx, 8));
                const float mn = fmaxf(m[r], mx);
                const float alpha = __expf(m[r] - mn);
                m[r] = mn;
                float rs = 0.f;
                #pragma unroll
                for (int t = 0; t < 4; ++t) {
                    const float p = __expf(sv[t][r] - mn);
                    sv[t][r] = p;
                    rs += p;
                }
                rs += __shfl_xor(rs, 1);
                rs += __shfl_xor(rs, 2);
                rs += __shfl_xor(rs, 4);
                rs += __shfl_xor(rs, 8);
                l[r] = l[r] * alpha + rs;
                #pragma unroll
                for (int dt = 0; dt < 4; ++dt) acc[dt][r] *= alpha;
            }

            #pragma unroll
            for (int t = 0; t < 4; ++t)
                #pragma unroll
                for (int r = 0; r < 4; ++r)
                    Ps[wave][quad * 4 + r][t * 16 + l16] = (__bf16)sv[t][r];
            __syncthreads();

            #pragma unroll
            for (int ks = 0; ks < 2; ++ks) {
                bf16x8 pa = *(const bf16x8*)&Ps[wave][l16][ks * 32 + quad * 8];
                #pragma unroll
                for (int dt = 0; dt < 4; ++dt) {
                    bf16x8 vbf = *(const bf16x8*)&Vt[dt * 16 + l16][ks * 32 + quad * 8];
                    acc[dt] = __builtin_amdgcn_mfma_f32_16x16x32_bf16(pa, vbf, acc[dt], 0, 0, 0);
                }
            }
        }

        float inv[4];
        #pragma unroll
        for (int r = 0; r < 4; ++r) inv[r] = 1.f / l[r];
        #pragma unroll
        for (int dt = 0; dt < 4; ++dt) {
            #pragma unroll
            for (int r = 0; r < 4; ++r) {
                const int row = qt + wave * 16 + quad * 4 + r;
                if (row < qend)
                    wv[(size_t)row * DV + h * 64 + dt * 16 + l16] =
                        __float2bfloat16(acc[dt][r] * inv[r]);
            }
        }
    }
}

// ---------------------------------------------------------------------------
extern "C" void kernel_launch(void* const* d_in, const int* in_sizes, int n_in,
                              void* d_out, int out_size, void* d_ws, size_t ws_size,
                              hipStream_t stream)
{
    const float* A     = (const float*)d_in[0];
    const float* B0    = (const float*)d_in[1];
    const int*   seg_q = (const int*)  d_in[2];
    const int*   seg_kv= (const int*)  d_in[3];
    const float* Wq    = (const float*)d_in[4];
    const float* bq    = (const float*)d_in[5];
    const float* Wk    = (const float*)d_in[6];
    const float* bk    = (const float*)d_in[7];
    const float* Wv    = (const float*)d_in[8];
    const float* bv    = (const float*)d_in[9];
    const float* Wf    = (const float*)d_in[10];
    const float* bf    = (const float*)d_in[11];
    float* out = (float*)d_out;

    // Workspace (bf16 elems), 29.6 MB total; all offsets 16B-aligned
    __hip_bfloat16* B0bf = (__hip_bfloat16*)d_ws;                 // 2048*1056
    __hip_bfloat16* Wqt  = B0bf + (size_t)TOTAL_KV * KVIN_P;      // 1024*1024
    __hip_bfloat16* Wkt  = Wqt  + (size_t)QIN * DQK;              // 1024*1056  \ fused
    __hip_bfloat16* Wvt  = Wkt  + (size_t)DQK * KVIN_P;           // 1024*1056  / [2048][1056]
    __hip_bfloat16* Wft  = Wvt  + (size_t)DV * KVIN_P;            // 1024*1024
    __hip_bfloat16* Abf  = Wft  + (size_t)DV * QIN;               // 2048*1024
    __hip_bfloat16* qb   = Abf  + (size_t)TOTAL_Q * QIN;          // 2048*1024
    __hip_bfloat16* kvb  = qb   + (size_t)TOTAL_Q * DQK;          // 2048*2048 fused [k|v]
    __hip_bfloat16* wvb  = Abf;  // alias: Abf dead after grouped QKV GEMM

    const dim3 b256(256);

    // 1) fused prep: casts + weight transposes + out-bias init
    prep_k<<<dim3(10368), b256, 0, stream>>>(A, B0, Wq, Wk, Wv, Wf, bf,
                                             Abf, B0bf, Wqt, Wkt, Wvt, Wft, out);

    // 2) grouped Q + KV projections (768 blocks; XCD-patched)
    gemm_qkv<<<dim3(768), b256, 0, stream>>>(Abf, Wqt, bq, qb,
                                             B0bf, Wkt, bk, bv, kvb);

    // 3) attention: block per (segment, head)
    attn_mfma<<<dim3(32 * 16), b256, 0, stream>>>(qb, kvb, kvb + 1024, seg_q, seg_kv, wvb);

    // 4) output projection, split-K=2, XCD-patched, atomic accumulate
    gemm_out<<<dim3(512), b256, 0, stream>>>(wvb, Wft, out, TOTAL_Q, QIN, DV);
}

// Round 12
// 164.005 us; speedup vs baseline: 1.3850x; 1.0251x over previous
//
#include <hip/hip_runtime.h>
#include <hip/hip_bf16.h>
#include <math.h>

#define TOTAL_Q   2048
#define TOTAL_KV  2048
#define QIN       1024
#define KVIN      1033
#define KVIN_P    1056      // KVIN padded to multiple of 32 (zero-filled)
#define DQK       1024
#define DV        1024
#define KVSTR     2048      // fused [k|v] row stride
#define SCALER    0.125f    // 1/sqrt(64)

typedef __bf16 bf16x8 __attribute__((ext_vector_type(8)));
typedef float  f32x4  __attribute__((ext_vector_type(4)));

// async global->LDS, 16 B per lane; LDS dest = wave-uniform base + lane*16
__device__ __forceinline__ void glds16(const __hip_bfloat16* g, __bf16* l)
{
    __builtin_amdgcn_global_load_lds(
        (const __attribute__((address_space(1))) void*)g,
        (__attribute__((address_space(3))) void*)l,
        16, 0, 0);
}

// XOR-swizzled LDS tile layout (proven R7): slot = quad ^ ((row>>1)&3)
__device__ __forceinline__ int stage_cc(int lane)
{
    return (((lane & 3) ^ ((lane >> 3) & 3)) * 8);
}
__device__ __forceinline__ int frag_off(int row, int quad)
{
    return row * 32 + ((quad ^ ((row >> 1) & 3)) * 8);
}

// ---------------------------------------------------------------------------
// Fused prep: casts + weight transposes (out-bias init removed; gemm_out now
// stores bias directly). 8320 blocks.
// ---------------------------------------------------------------------------
__global__ __launch_bounds__(256)
void prep_k(const float* __restrict__ A,  const float* __restrict__ B0,
            const float* __restrict__ Wq, const float* __restrict__ Wk,
            const float* __restrict__ Wv, const float* __restrict__ Wf,
            __hip_bfloat16* __restrict__ Abf, __hip_bfloat16* __restrict__ B0bf,
            __hip_bfloat16* __restrict__ Wqt, __hip_bfloat16* __restrict__ Wkt,
            __hip_bfloat16* __restrict__ Wvt, __hip_bfloat16* __restrict__ Wft)
{
    const int b   = blockIdx.x;
    const int tid = threadIdx.x;

    if (b < 2048) {                       // ---- cast A
        int i = (b * 256 + tid) * 4;
        float4 f = *(const float4*)(A + i);
        __hip_bfloat16 o[4] = { __float2bfloat16(f.x), __float2bfloat16(f.y),
                                __float2bfloat16(f.z), __float2bfloat16(f.w) };
        *(uint2*)(Abf + i) = *(const uint2*)o;
        return;
    }
    if (b < 4160) {                       // ---- cast+pad B0
        int idx = ((b - 2048) * 256 + tid) * 4;
        int r = idx / KVIN_P, c = idx - r * KVIN_P;
        __hip_bfloat16 o[4];
        #pragma unroll
        for (int j = 0; j < 4; ++j)
            o[j] = __float2bfloat16((c + j < KVIN) ? B0[(size_t)r * KVIN + c + j] : 0.f);
        *(uint2*)(B0bf + idx) = *(const uint2*)o;
        return;
    }

    // ---- transposes: W[K][1024] -> Wt[1024][Kp], zero-fill k >= K
    const float* W; __hip_bfloat16* Wt; int K, Kp, k0, n0;
    if (b < 6208) {
        int z = b - 4160;
        W  = (z >= 1024) ? Wf : Wq;
        Wt = (z >= 1024) ? Wft : Wqt;
        K = 1024; Kp = 1024;
        int rem = z & 1023;
        k0 = (rem & 31) * 32; n0 = (rem >> 5) * 32;
    } else {
        int z = b - 6208;
        W  = (z >= 1056) ? Wv : Wk;
        Wt = (z >= 1056) ? Wvt : Wkt;
        K = KVIN; Kp = KVIN_P;
        int rem = (z >= 1056) ? z - 1056 : z;
        k0 = (rem % 33) * 32; n0 = (rem / 33) * 32;
    }
    const int tx = tid & 31, ty = tid >> 5;   // (32,8)
    __shared__ float tile[32][33];
    #pragma unroll
    for (int i = 0; i < 4; ++i) {
        int k = k0 + ty + i * 8;
        tile[ty + i * 8][tx] = (k < K) ? W[(size_t)k * 1024 + n0 + tx] : 0.f;
    }
    __syncthreads();
    #pragma unroll
    for (int i = 0; i < 4; ++i) {
        int n = n0 + ty + i * 8;
        Wt[(size_t)n * Kp + k0 + tx] = __float2bfloat16(tile[tx][ty + i * 8]);
    }
}

// ---------------------------------------------------------------------------
// Grouped Q + fused-KV projection (R11, unchanged): XCD-patched, BM=128,
// BN=64, BK=32, 768 blocks.
// ---------------------------------------------------------------------------
__global__ __launch_bounds__(256)
void gemm_qkv(const __hip_bfloat16* __restrict__ Abf,
              const __hip_bfloat16* __restrict__ Wqt,
              const float* __restrict__ bq,
              __hip_bfloat16* __restrict__ qb,
              const __hip_bfloat16* __restrict__ B0bf,
              const __hip_bfloat16* __restrict__ Wkvt,
              const float* __restrict__ bk, const float* __restrict__ bv,
              __hip_bfloat16* __restrict__ kvb)
{
    __shared__ __bf16 As[128 * 32];   // 8 KB
    __shared__ __bf16 Bs[64 * 32];    // 4 KB

    int b = blockIdx.x;
    const __hip_bfloat16 *Ag, *Btg; const float *bias0, *bias1;
    __hip_bfloat16* C; int N, K, bx, by;
    if (b < 256) {        // Q: 16 cols x 16 rows, XCD patch 4x8
        Ag = Abf; Btg = Wqt; bias0 = bq; bias1 = bq; C = qb;
        N = 1024; K = 1024;
        int xcd = b & 7, i = b >> 3;
        int px = xcd & 3, py = xcd >> 2;
        bx = px * 4 + (i & 3);
        by = py * 8 + (i >> 2);
    } else {              // KV: 32 cols x 16 rows, XCD patch 8x8
        b -= 256;
        Ag = B0bf; Btg = Wkvt; bias0 = bk; bias1 = bv; C = kvb;
        N = 2048; K = KVIN_P;
        int xcd = b & 7, i = b >> 3;
        int px = xcd & 3, py = xcd >> 2;
        bx = px * 8 + (i & 7);
        by = py * 8 + (i >> 3);
    }
    const int row0 = by * 128, col0 = bx * 64;

    const int tid  = threadIdx.x;
    const int wave = tid >> 6, lane = tid & 63;
    const int quad = lane >> 4, l16 = lane & 15;
    const int wm = (wave >> 1) * 64, wn = (wave & 1) * 32;

    const int cr = lane >> 2;
    const int cc = stage_cc(lane);

    const __hip_bfloat16* gsrc[3];
    __bf16* ldst[3];
    #pragma unroll
    for (int i = 0; i < 3; ++i) {
        int c = wave * 3 + i;
        if (c < 8) {
            gsrc[i] = Ag  + (size_t)(row0 + c * 16 + cr) * K + cc;
            ldst[i] = &As[c * 512];
        } else {
            gsrc[i] = Btg + (size_t)(col0 + (c - 8) * 16 + cr) * K + cc;
            ldst[i] = &Bs[(c - 8) * 512];
        }
    }

    f32x4 acc[4][2] = {};

    for (int k0 = 0; k0 < K; k0 += 32) {
        #pragma unroll
        for (int i = 0; i < 3; ++i)
            glds16(gsrc[i] + k0, ldst[i]);
        __syncthreads();

        bf16x8 af[4], bfr[2];
        #pragma unroll
        for (int mi = 0; mi < 4; ++mi)
            af[mi] = *(const bf16x8*)&As[frag_off(wm + mi * 16 + l16, quad)];
        #pragma unroll
        for (int ni = 0; ni < 2; ++ni)
            bfr[ni] = *(const bf16x8*)&Bs[frag_off(wn + ni * 16 + l16, quad)];

        #pragma unroll
        for (int mi = 0; mi < 4; ++mi)
            #pragma unroll
            for (int ni = 0; ni < 2; ++ni)
                acc[mi][ni] = __builtin_amdgcn_mfma_f32_16x16x32_bf16(
                    af[mi], bfr[ni], acc[mi][ni], 0, 0, 0);
        __syncthreads();
    }

    #pragma unroll
    for (int mi = 0; mi < 4; ++mi) {
        #pragma unroll
        for (int ni = 0; ni < 2; ++ni) {
            const int col = col0 + wn + ni * 16 + l16;
            const float bia = (col < 1024) ? bias0[col] : bias1[col - 1024];
            #pragma unroll
            for (int r = 0; r < 4; ++r) {
                const int row = row0 + wm + mi * 16 + quad * 4 + r;
                C[(size_t)row * N + col] = __float2bfloat16(acc[mi][ni][r] + bia);
            }
        }
    }
}

// ---------------------------------------------------------------------------
// Output projection: single-K, plain stores with fused bias (atomics removed).
// 256 blocks, XCD patch 4x8 over the 16x16 tile grid. BM=128, BN=64, BK=32.
// ---------------------------------------------------------------------------
__global__ __launch_bounds__(256)
void gemm_out(const __hip_bfloat16* __restrict__ A,
              const __hip_bfloat16* __restrict__ Bt,
              const float* __restrict__ bias,
              float* __restrict__ C,
              int M, int N, int K)
{
    __shared__ __bf16 As[128 * 32];
    __shared__ __bf16 Bs[64 * 32];

    // decode: 16 cols x 16 rows; XCD patch 4 cols x 8 rows
    int b = blockIdx.x;
    const int xcd = b & 7, i = b >> 3;            // i in [0,32)
    const int px = xcd & 3, py = xcd >> 2;
    const int bx = px * 4 + (i & 3);
    const int by = py * 8 + (i >> 2);

    const int tid  = threadIdx.x;
    const int wave = tid >> 6, lane = tid & 63;
    const int quad = lane >> 4, l16 = lane & 15;
    const int wm = (wave >> 1) * 64;
    const int wn = (wave & 1) * 32;
    const int row0 = by * 128, col0 = bx * 64;

    const int cr = lane >> 2;
    const int cc = stage_cc(lane);

    const __hip_bfloat16* gsrc[3];
    __bf16* ldst[3];
    #pragma unroll
    for (int i2 = 0; i2 < 3; ++i2) {
        int c = wave * 3 + i2;
        if (c < 8) {
            gsrc[i2] = A  + (size_t)(row0 + c * 16 + cr) * K + cc;
            ldst[i2] = &As[c * 512];
        } else {
            gsrc[i2] = Bt + (size_t)(col0 + (c - 8) * 16 + cr) * K + cc;
            ldst[i2] = &Bs[(c - 8) * 512];
        }
    }

    f32x4 acc[4][2] = {};

    for (int k0 = 0; k0 < K; k0 += 32) {
        #pragma unroll
        for (int i2 = 0; i2 < 3; ++i2)
            glds16(gsrc[i2] + k0, ldst[i2]);
        __syncthreads();

        bf16x8 af[4], bfr[2];
        #pragma unroll
        for (int mi = 0; mi < 4; ++mi)
            af[mi] = *(const bf16x8*)&As[frag_off(wm + mi * 16 + l16, quad)];
        #pragma unroll
        for (int ni = 0; ni < 2; ++ni)
            bfr[ni] = *(const bf16x8*)&Bs[frag_off(wn + ni * 16 + l16, quad)];

        #pragma unroll
        for (int mi = 0; mi < 4; ++mi)
            #pragma unroll
            for (int ni = 0; ni < 2; ++ni)
                acc[mi][ni] = __builtin_amdgcn_mfma_f32_16x16x32_bf16(
                    af[mi], bfr[ni], acc[mi][ni], 0, 0, 0);
        __syncthreads();
    }

    #pragma unroll
    for (int mi = 0; mi < 4; ++mi) {
        #pragma unroll
        for (int ni = 0; ni < 2; ++ni) {
            const int col = col0 + wn + ni * 16 + l16;
            const float bia = bias[col];
            #pragma unroll
            for (int r = 0; r < 4; ++r) {
                const int row = row0 + wm + mi * 16 + quad * 4 + r;
                C[(size_t)row * N + col] = acc[mi][ni][r] + bia;
            }
        }
    }
}

// ---------------------------------------------------------------------------
// MFMA flash attention over ragged segments (unchanged, proven).
// ---------------------------------------------------------------------------
#define CH 64

__global__ __launch_bounds__(256)
void attn_mfma(const __hip_bfloat16* __restrict__ qg,
               const __hip_bfloat16* __restrict__ kg,   // kvb
               const __hip_bfloat16* __restrict__ vg,   // kvb + 1024
               const int* __restrict__ seg_q, const int* __restrict__ seg_kv,
               __hip_bfloat16* __restrict__ wv)
{
    const int h = blockIdx.x & 15;
    const int s = blockIdx.x >> 4;

    __shared__ int sb[4];
    __shared__ __bf16 Ks[CH][72];
    __shared__ __bf16 Vt[64][CH + 8];
    __shared__ __bf16 Ps[4][16][CH + 8];

    if (threadIdx.x == 0) {
        int lo, hi;
        lo = 0; hi = TOTAL_Q;
        while (lo < hi) { int m = (lo + hi) >> 1; if (seg_q[m] <  s) lo = m + 1; else hi = m; }
        sb[0] = lo;
        hi = TOTAL_Q;
        while (lo < hi) { int m = (lo + hi) >> 1; if (seg_q[m] <= s) lo = m + 1; else hi = m; }
        sb[1] = lo;
        lo = 0; hi = TOTAL_KV;
        while (lo < hi) { int m = (lo + hi) >> 1; if (seg_kv[m] <  s) lo = m + 1; else hi = m; }
        sb[2] = lo;
        hi = TOTAL_KV;
        while (lo < hi) { int m = (lo + hi) >> 1; if (seg_kv[m] <= s) lo = m + 1; else hi = m; }
        sb[3] = lo;
    }
    __syncthreads();
    const int qbeg = sb[0], qend = sb[1], kbeg = sb[2], kend = sb[3];

    const int tid  = threadIdx.x;
    const int wave = tid >> 6, lane = tid & 63;
    const int quad = lane >> 4, l16 = lane & 15;

    for (int qt = qbeg; qt < qend; qt += 64) {
        const int qrow = qt + wave * 16 + l16;
        const int qrc  = min(qrow, qend - 1);
        bf16x8 qf[2];
        qf[0] = *(const bf16x8*)(qg + (size_t)qrc * DQK + h * 64 + quad * 8);
        qf[1] = *(const bf16x8*)(qg + (size_t)qrc * DQK + h * 64 + 32 + quad * 8);

        float m[4]  = { -1e30f, -1e30f, -1e30f, -1e30f };
        float l[4]  = { 0.f, 0.f, 0.f, 0.f };
        f32x4 acc[4] = {};

        for (int c0 = kbeg; c0 < kend; c0 += CH) {
            const int cl = min(CH, kend - c0);
            __syncthreads();

            #pragma unroll
            for (int it = 0; it < 2; ++it) {
                int e = (it * 256 + tid) * 8;
                int r = e >> 6, d = e & 63;
                bf16x8 z = {};
                if (r < cl)
                    z = *(const bf16x8*)(kg + (size_t)(c0 + r) * KVSTR + h * 64 + d);
                *(bf16x8*)&Ks[r][d] = z;
            }
            #pragma unroll
            for (int it = 0; it < 4; ++it) {
                int e = (it * 256 + tid) * 4;
                int r = e >> 6, d = e & 63;
                __bf16 t0 = 0, t1 = 0, t2 = 0, t3 = 0;
                if (r < cl) {
                    bf16x8 vv;
                    uint2 uu = *(const uint2*)(vg + (size_t)(c0 + r) * KVSTR + h * 64 + d);
                    *(uint2*)&vv = uu;
                    t0 = vv[0]; t1 = vv[1]; t2 = vv[2]; t3 = vv[3];
                }
                Vt[d + 0][r] = t0; Vt[d + 1][r] = t1;
                Vt[d + 2][r] = t2; Vt[d + 3][r] = t3;
            }
            __syncthreads();

            f32x4 sc[4];
            #pragma unroll
            for (int t = 0; t < 4; ++t) {
                bf16x8 b0 = *(const bf16x8*)&Ks[t * 16 + l16][quad * 8];
                bf16x8 b1 = *(const bf16x8*)&Ks[t * 16 + l16][32 + quad * 8];
                f32x4 z = {};
                z = __builtin_amdgcn_mfma_f32_16x16x32_bf16(qf[0], b0, z, 0, 0, 0);
                z = __builtin_amdgcn_mfma_f32_16x16x32_bf16(qf[1], b1, z, 0, 0, 0);
                sc[t] = z;
            }

            float sv[4][4];
            #pragma unroll
            for (int t = 0; t < 4; ++t) {
                const bool ok = (c0 + t * 16 + l16) < kend;
                #pragma unroll
                for (int r = 0; r < 4; ++r)
                    sv[t][r] = ok ? sc[t][r] * SCALER : -1e30f;
            }

            #pragma unroll
            for (int r = 0; r < 4; ++r) {
                float mx = fmaxf(fmaxf(sv[0][r], sv[1][r]), fmaxf(sv[2][r], sv[3][r]));
                mx = fmaxf(mx, __shfl_xor(mx, 1));
                mx = fmaxf(mx, __shfl_xor(mx, 2));
                mx = fmaxf(mx, __shfl_xor(mx, 4));
                mx = fmaxf(mx, __shfl_xor(mx, 8));
                const float mn = fmaxf(m[r], mx);
                const float alpha = __expf(m[r] - mn);
                m[r] = mn;
                float rs = 0.f;
                #pragma unroll
                for (int t = 0; t < 4; ++t) {
                    const float p = __expf(sv[t][r] - mn);
                    sv[t][r] = p;
                    rs += p;
                }
                rs += __shfl_xor(rs, 1);
                rs += __shfl_xor(rs, 2);
                rs += __shfl_xor(rs, 4);
                rs += __shfl_xor(rs, 8);
                l[r] = l[r] * alpha + rs;
                #pragma unroll
                for (int dt = 0; dt < 4; ++dt) acc[dt][r] *= alpha;
            }

            #pragma unroll
            for (int t = 0; t < 4; ++t)
                #pragma unroll
                for (int r = 0; r < 4; ++r)
                    Ps[wave][quad * 4 + r][t * 16 + l16] = (__bf16)sv[t][r];
            __syncthreads();

            #pragma unroll
            for (int ks = 0; ks < 2; ++ks) {
                bf16x8 pa = *(const bf16x8*)&Ps[wave][l16][ks * 32 + quad * 8];
                #pragma unroll
                for (int dt = 0; dt < 4; ++dt) {
                    bf16x8 vbf = *(const bf16x8*)&Vt[dt * 16 + l16][ks * 32 + quad * 8];
                    acc[dt] = __builtin_amdgcn_mfma_f32_16x16x32_bf16(pa, vbf, acc[dt], 0, 0, 0);
                }
            }
        }

        float inv[4];
        #pragma unroll
        for (int r = 0; r < 4; ++r) inv[r] = 1.f / l[r];
        #pragma unroll
        for (int dt = 0; dt < 4; ++dt) {
            #pragma unroll
            for (int r = 0; r < 4; ++r) {
                const int row = qt + wave * 16 + quad * 4 + r;
                if (row < qend)
                    wv[(size_t)row * DV + h * 64 + dt * 16 + l16] =
                        __float2bfloat16(acc[dt][r] * inv[r]);
            }
        }
    }
}

// ---------------------------------------------------------------------------
extern "C" void kernel_launch(void* const* d_in, const int* in_sizes, int n_in,
                              void* d_out, int out_size, void* d_ws, size_t ws_size,
                              hipStream_t stream)
{
    const float* A     = (const float*)d_in[0];
    const float* B0    = (const float*)d_in[1];
    const int*   seg_q = (const int*)  d_in[2];
    const int*   seg_kv= (const int*)  d_in[3];
    const float* Wq    = (const float*)d_in[4];
    const float* bq    = (const float*)d_in[5];
    const float* Wk    = (const float*)d_in[6];
    const float* bk    = (const float*)d_in[7];
    const float* Wv    = (const float*)d_in[8];
    const float* bv    = (const float*)d_in[9];
    const float* Wf    = (const float*)d_in[10];
    const float* bf    = (const float*)d_in[11];
    float* out = (float*)d_out;

    // Workspace (bf16 elems), 29.6 MB total; all offsets 16B-aligned
    __hip_bfloat16* B0bf = (__hip_bfloat16*)d_ws;                 // 2048*1056
    __hip_bfloat16* Wqt  = B0bf + (size_t)TOTAL_KV * KVIN_P;      // 1024*1024
    __hip_bfloat16* Wkt  = Wqt  + (size_t)QIN * DQK;              // 1024*1056  \ fused
    __hip_bfloat16* Wvt  = Wkt  + (size_t)DQK * KVIN_P;           // 1024*1056  / [2048][1056]
    __hip_bfloat16* Wft  = Wvt  + (size_t)DV * KVIN_P;            // 1024*1024
    __hip_bfloat16* Abf  = Wft  + (size_t)DV * QIN;               // 2048*1024
    __hip_bfloat16* qb   = Abf  + (size_t)TOTAL_Q * QIN;          // 2048*1024
    __hip_bfloat16* kvb  = qb   + (size_t)TOTAL_Q * DQK;          // 2048*2048 fused [k|v]
    __hip_bfloat16* wvb  = Abf;  // alias: Abf dead after grouped QKV GEMM

    const dim3 b256(256);

    // 1) fused prep: casts + weight transposes
    prep_k<<<dim3(8320), b256, 0, stream>>>(A, B0, Wq, Wk, Wv, Wf,
                                            Abf, B0bf, Wqt, Wkt, Wvt, Wft);

    // 2) grouped Q + KV projections (768 blocks; XCD-patched)
    gemm_qkv<<<dim3(768), b256, 0, stream>>>(Abf, Wqt, bq, qb,
                                             B0bf, Wkt, bk, bv, kvb);

    // 3) attention: block per (segment, head)
    attn_mfma<<<dim3(32 * 16), b256, 0, stream>>>(qb, kvb, kvb + 1024, seg_q, seg_kv, wvb);

    // 4) output projection: plain store + fused bias (256 blocks, XCD-patched)
    gemm_out<<<dim3(256), b256, 0, stream>>>(wvb, Wft, bf, out, TOTAL_Q, QIN, DV);
}